// Round 7
// baseline (341.150 us; speedup 1.0000x reference)
//
#include <hip/hip_runtime.h>
#include <hip/hip_bf16.h>

// ---------------- problem constants ----------------
#define QSCALE   0.08838834764831845f               // 1/sqrt(128)
#define QKSCALE  0.1275174468755322f                // QSCALE * log2(e)

typedef __attribute__((ext_vector_type(8))) short bh8;   // 8 bf16 (4 VGPRs)
typedef __attribute__((ext_vector_type(4))) float fx4;   // 4 fp32
typedef __attribute__((ext_vector_type(4))) short sh4;

typedef const __attribute__((address_space(1))) unsigned GAu;
typedef __attribute__((address_space(3))) unsigned LAu;

__device__ __forceinline__ short f2bf(float f) {
    unsigned u = __float_as_uint(f);
    unsigned r = u + 0x7fffu + ((u >> 16) & 1u);   // RNE
    return (short)(r >> 16);
}

__device__ __forceinline__ unsigned pk_bf16(float x, float y) {
    union { __hip_bfloat162 h; unsigned u; } cv;
    cv.h = __float22bfloat162_rn(float2{x, y});    // x -> low short, y -> high short
    return cv.u;
}

// ---------------- conversion: X fp32 -> bf16 ----------------
__global__ __launch_bounds__(256) void cvt_x(const float* __restrict__ x,
                                             short* __restrict__ o) {
    int i = blockIdx.x * 256 + threadIdx.x;
    float4 v = ((const float4*)x)[i];
    sh4 s;
    s.x = f2bf(v.x); s.y = f2bf(v.y); s.z = f2bf(v.z); s.w = f2bf(v.w);
    ((sh4*)o)[i] = s;
}

// ---------------- transpose: W [K][N] fp32 -> Wt [N][K] bf16 ----------------
__global__ __launch_bounds__(256) void transpose_w(const float* __restrict__ w,
                                                   short* __restrict__ wt,
                                                   int K, int N) {
    __shared__ float tile[32][33];
    int nb = blockIdx.x, kb = blockIdx.y;
    int tx = threadIdx.x & 31, ty = threadIdx.x >> 5;
#pragma unroll
    for (int j = 0; j < 4; ++j) {
        int k = kb * 32 + ty + j * 8;
        tile[ty + j * 8][tx] = w[(size_t)k * N + nb * 32 + tx];
    }
    __syncthreads();
#pragma unroll
    for (int j = 0; j < 4; ++j) {
        int n = nb * 32 + ty + j * 8;
        wt[(size_t)n * K + kb * 32 + tx] = f2bf(tile[tx][ty + j * 8]);
    }
}

// ---------------- fused QKV projection GEMM ----------------
// C[4096 x 3072]: n-tiles 0..15 -> Q, 16..19 -> K, 20..23 -> V
// Epilogue:
//   Q  -> Qb[b][h][s][128] bf16, scaled by QKSCALE
//   K  -> Kpk: B-fragment-packed. frag (b,g,kt,nt,ks): lane=quad*16+l16, j<8
//         holds K[kt*64 + nt*16 + l16][ks*32 + quad*8 + j]
//   V  -> Vpk: B-fragment-packed. frag (b,g,kt,nt,ts): lane=quad*16+l16, j<8
//         holds V[kt*64 + ts*32 + quad*8 + j][nt*16 + l16]
__global__ __launch_bounds__(256) void proj_gemm(
    const short* __restrict__ X,     // [4096][2048] bf16
    const short* __restrict__ WqT,   // [2048][2048] bf16 (N-major)
    const short* __restrict__ WkT,   // [512][2048]
    const short* __restrict__ WvT,   // [512][2048]
    const float* __restrict__ bq, const float* __restrict__ bk,
    const float* __restrict__ bv,
    short* __restrict__ Qb, short* __restrict__ Kpk, short* __restrict__ Vpk) {
    __shared__ short As[128 * 32];
    __shared__ short Bs[128 * 32];

    const int tid = threadIdx.x;
    const int bm = blockIdx.x;      // 0..31
    const int ntg = blockIdx.y;     // 0..23

    const short* Wm; const float* bias; int col0, kind;
    if (ntg < 16)      { Wm = WqT; bias = bq; col0 = ntg * 128;        kind = 0; }
    else if (ntg < 20) { Wm = WkT; bias = bk; col0 = (ntg - 16) * 128; kind = 1; }
    else               { Wm = WvT; bias = bv; col0 = (ntg - 20) * 128; kind = 2; }

    const int w = tid >> 6, lane = tid & 63, quad = lane >> 4, l16 = lane & 15;

    fx4 acc[2][8];
#pragma unroll
    for (int i = 0; i < 2; ++i)
#pragma unroll
        for (int j = 0; j < 8; ++j) acc[i][j] = fx4{0.f, 0.f, 0.f, 0.f};

    const int srow = w * 16 + (lane >> 2);
    const int scol = (((lane & 3) ^ ((lane >> 2) & 3)) * 8);
    const short* Ag = X + (size_t)(bm * 128 + srow) * 2048 + scol;
    const short* Bg = Wm + (size_t)(col0 + srow) * 2048 + scol;
    short* AsW = As + w * 512;
    short* BsW = Bs + w * 512;

    const int fchunk = (quad ^ (l16 & 3)) * 8;
    const short* afp0 = As + (w * 32 + l16) * 32 + fchunk;
    const short* afp1 = As + (w * 32 + 16 + l16) * 32 + fchunk;

    for (int kt = 0; kt < 64; ++kt) {
        const int k0 = kt * 32;
        __syncthreads();
#pragma unroll
        for (int j = 0; j < 2; ++j) {
            __builtin_amdgcn_global_load_lds((GAu*)(Ag + (size_t)(j * 64) * 2048 + k0),
                                             (LAu*)(AsW + j * 2048), 16, 0, 0);
            __builtin_amdgcn_global_load_lds((GAu*)(Bg + (size_t)(j * 64) * 2048 + k0),
                                             (LAu*)(BsW + j * 2048), 16, 0, 0);
        }
        __syncthreads();
        bh8 af0 = *(const bh8*)afp0;
        bh8 af1 = *(const bh8*)afp1;
#pragma unroll
        for (int nt = 0; nt < 8; ++nt) {
            bh8 bf = *(const bh8*)(Bs + (nt * 16 + l16) * 32 + fchunk);
            acc[0][nt] = __builtin_amdgcn_mfma_f32_16x16x32_bf16(af0, bf, acc[0][nt], 0, 0, 0);
            acc[1][nt] = __builtin_amdgcn_mfma_f32_16x16x32_bf16(af1, bf, acc[1][nt], 0, 0, 0);
        }
    }

    // epilogue: row = bm*128 + w*32 + mt*16 + quad*4 + r ; col = col0 + nt*16 + l16
#pragma unroll
    for (int mt = 0; mt < 2; ++mt) {
        int srow2 = bm * 128 + w * 32 + mt * 16 + quad * 4;
#pragma unroll
        for (int nt = 0; nt < 8; ++nt) {
            int c = col0 + nt * 16 + l16;
            float bval = bias[c];
#pragma unroll
            for (int r = 0; r < 4; ++r) {
                int sg = srow2 + r;
                int b = sg >> 11, s = sg & 2047;
                float v = acc[mt][nt][r] + bval;
                int hd = c & 127;
                if (kind == 0) {
                    v *= QKSCALE;  // fold 1/sqrt(d)*log2(e) into Q
                    int h = c >> 7;
                    Qb[(((size_t)(b * 16 + h) * 2048 + s) << 7) + hd] = f2bf(v);
                } else if (kind == 1) {
                    int g = c >> 7;
                    int ktt = s >> 6, tl = s & 63;
                    int fnt = tl >> 4, fl16 = tl & 15;
                    int ks = hd >> 5, qd = (hd >> 3) & 3, j = hd & 7;
                    size_t frag = (((size_t)(b * 4 + g) * 32 + ktt) * 16 + fnt * 4 + ks);
                    Kpk[frag * 512 + (qd * 16 + fl16) * 8 + j] = f2bf(v);
                } else {
                    int g = c >> 7;
                    int ktt = s >> 6, tl = s & 63;
                    int ts = tl >> 5, qd = (tl >> 3) & 3, j = tl & 7;
                    int fnt = hd >> 4, fl16 = hd & 15;
                    size_t frag = (((size_t)(b * 4 + g) * 32 + ktt) * 16 + fnt * 2 + ts);
                    Vpk[frag * 512 + (qd * 16 + fl16) * 8 + j] = f2bf(v);
                }
            }
        }
    }
}

// ---------------- flash attention: t-split waves, zero in-loop barriers ----------------
// 4096 blocks = (gb=b*4+g in bid%8 for XCD-local KV, rep, qt 0..127).
// Block = 16 q-rows; wave w owns t-slice [w*32, w*32+32) of each 128-t KV tile.
// Every K/V frag loaded exactly once per block (coalesced 1KB, L2-local);
// P wave-private; ctx/l reduced across the 4 waves once at the end.
__global__ __launch_bounds__(256, 4) void attn(
    const short* __restrict__ Qb,   // [B][HQ][S][128] bf16, pre-scaled by QKSCALE
    const short* __restrict__ Kpk,  // packed B-frags
    const short* __restrict__ Vpk,  // packed B-frags
    float* __restrict__ out) {      // [B][S][D] fp32
    // Red[w][row 16][132] fp32 for the final cross-wave ctx reduction (33 KB).
    // During the loop its first 5KB is aliased as the wave-private P buffer:
    // Ps row (w,m) = PsB + (w*16+m)*20 dwords; dword i<16 = bf16 pair (t=i, t=i+16).
    __shared__ __align__(16) float Red[4][16][132];
    __shared__ float Lbuf[4][16];
    unsigned* PsB = (unsigned*)&Red[0][0][0];

    const int bid = blockIdx.x;
    const int gb = bid & 7;              // XCD selector = b*4+g
    const int rep = (bid >> 3) & 3;
    const int qt = bid >> 5;             // 0..127 (16-row q tiles)
    const int b = gb >> 2, g = gb & 3;
    const int h = rep * 4 + g;
    const int tid = threadIdx.x, w = tid >> 6, lane = tid & 63;
    const int quad = lane >> 4, l16 = lane & 15;

    // Q A-frags for the block's 16 rows (shared by all waves)
    bh8 qf[4];
    {
        int s = qt * 16 + l16;
        const short* qp = Qb + (((size_t)(b * 16 + h) * 2048 + s) << 7);
#pragma unroll
        for (int ks = 0; ks < 4; ++ks)
            qf[ks] = *(const bh8*)(qp + ks * 32 + quad * 8);
    }

    // per-wave K/V frag bases (ktt = kt*2 + (w>>1); K fnt = (w&1)*2+nt; V ts = w&1)
    const size_t gbase = (size_t)gb * 32 * 8192;
    const short* kbase = Kpk + gbase + ((size_t)(w >> 1) * 16 + (size_t)(w & 1) * 8) * 512 + lane * 8;
    const short* vbase = Vpk + gbase + ((size_t)(w >> 1) * 16 + (size_t)(w & 1)) * 512 + lane * 8;

    fx4 ctx[8];
#pragma unroll
    for (int j = 0; j < 8; ++j) ctx[j] = fx4{0.f, 0.f, 0.f, 0.f};
    float l_part[4] = {0.f, 0.f, 0.f, 0.f};

    unsigned* psrow_w = PsB + (w * 16 + quad * 4) * 20 + l16;      // write base (row quad*4+r)
    const unsigned* psrow_r = PsB + (w * 16 + l16) * 20 + (quad & 1) * 8;  // read base
    const unsigned pat = (quad >> 1) ? 0x07060302u : 0x05040100u;

    for (int kt = 0; kt < 16; ++kt) {
        const short* kp = kbase + (size_t)kt * 16384;   // 2*16*512 shorts per kt step
        const short* vp = vbase + (size_t)kt * 16384;

        // ---- K frags (8 x coalesced 1KB) + QK^T ----
        fx4 sc[2];
        sc[0] = fx4{0.f, 0.f, 0.f, 0.f};
        sc[1] = fx4{0.f, 0.f, 0.f, 0.f};
#pragma unroll
        for (int ks = 0; ks < 4; ++ks) {
            bh8 k0 = *(const bh8*)(kp + ks * 512);
            bh8 k1 = *(const bh8*)(kp + (4 + ks) * 512);
            sc[0] = __builtin_amdgcn_mfma_f32_16x16x32_bf16(qf[ks], k0, sc[0], 0, 0, 0);
            sc[1] = __builtin_amdgcn_mfma_f32_16x16x32_bf16(qf[ks], k1, sc[1], 0, 0, 0);
        }

        // ---- exp2 + l partials + packed P write (wave-private, no barrier) ----
#pragma unroll
        for (int r = 0; r < 4; ++r) {
            float p0 = __builtin_amdgcn_exp2f(sc[0][r]);
            float p1 = __builtin_amdgcn_exp2f(sc[1][r]);
            l_part[r] += p0 + p1;
            psrow_w[r * 20] = pk_bf16(p0, p1);     // dword l16 of row quad*4+r
        }

        // ---- read P as A-frag [m=l16][t=quad*8+j] via 2xb128 + v_perm ----
        bh8 pa;
        {
            uint4 lo = *(const uint4*)(psrow_r);
            uint4 hi = *(const uint4*)(psrow_r + 4);
            unsigned dw[8] = {lo.x, lo.y, lo.z, lo.w, hi.x, hi.y, hi.z, hi.w};
            unsigned a[4];
#pragma unroll
            for (int j = 0; j < 4; ++j)
                a[j] = __builtin_amdgcn_perm(dw[2 * j + 1], dw[2 * j], pat);
            pa = *(const bh8*)a;
        }

        // ---- V frags (8 x coalesced 1KB) + PV ----
#pragma unroll
        for (int nt = 0; nt < 8; ++nt) {
            bh8 vf = *(const bh8*)(vp + nt * 1024);
            ctx[nt] = __builtin_amdgcn_mfma_f32_16x16x32_bf16(pa, vf, ctx[nt], 0, 0, 0);
        }
    }

    // ---- cross-wave reduction: ctx and l over the 4 t-slices ----
    // wave-level l reduce over l16 first
    float lrow = l_part[0];   // keep per-r values; reduce each over l16 lanes
    (void)lrow;
#pragma unroll
    for (int r = 0; r < 4; ++r) {
        float v = l_part[r];
        v += __shfl_xor(v, 1);
        v += __shfl_xor(v, 2);
        v += __shfl_xor(v, 4);
        v += __shfl_xor(v, 8);
        l_part[r] = v;
    }
    __syncthreads();   // all waves done with Ps region before Red overwrites it
#pragma unroll
    for (int nt = 0; nt < 8; ++nt)
#pragma unroll
        for (int r = 0; r < 4; ++r)
            Red[w][quad * 4 + r][nt * 16 + l16] = ctx[nt][r];
    if (l16 == 0) {
#pragma unroll
        for (int r = 0; r < 4; ++r)
            Lbuf[w][quad * 4 + r] = l_part[r];
    }
    __syncthreads();

    // 512 float4 outputs; each thread sums 4 wave-partials for 2 of them
#pragma unroll
    for (int c = 0; c < 2; ++c) {
        int f = tid + 256 * c;          // 0..511
        int row = f >> 5, c4 = (f & 31) * 4;
        float4 s0 = *(const float4*)&Red[0][row][c4];
        float4 s1 = *(const float4*)&Red[1][row][c4];
        float4 s2 = *(const float4*)&Red[2][row][c4];
        float4 s3 = *(const float4*)&Red[3][row][c4];
        float inv = 1.f / (Lbuf[0][row] + Lbuf[1][row] + Lbuf[2][row] + Lbuf[3][row]);
        float4 o;
        o.x = (s0.x + s1.x + s2.x + s3.x) * inv;
        o.y = (s0.y + s1.y + s2.y + s3.y) * inv;
        o.z = (s0.z + s1.z + s2.z + s3.z) * inv;
        o.w = (s0.w + s1.w + s2.w + s3.w) * inv;
        int s = qt * 16 + row;
        *(float4*)&out[((size_t)b * 2048 + s) * 2048 + h * 128 + c4] = o;
    }
}

// ---------------- launcher ----------------
extern "C" void kernel_launch(void* const* d_in, const int* in_sizes, int n_in,
                              void* d_out, int out_size, void* d_ws, size_t ws_size,
                              hipStream_t stream) {
    const float* hs = (const float*)d_in[0];
    const float* Wq = (const float*)d_in[1];
    const float* bq = (const float*)d_in[2];
    const float* Wk = (const float*)d_in[3];
    const float* bk = (const float*)d_in[4];
    const float* Wv = (const float*)d_in[5];
    const float* bv = (const float*)d_in[6];
    float* out = (float*)d_out;

    char* ws = (char*)d_ws;
    short* Xbf = (short*)(ws);                       // 16 MiB
    short* WqT = (short*)(ws + 16777216);            // 8 MiB
    short* WkT = (short*)(ws + 25165824);            // 2 MiB
    short* WvT = (short*)(ws + 27262976);            // 2 MiB
    short* Qb  = (short*)(ws + 29360128);            // 16 MiB
    short* Kpk = (short*)(ws + 46137344);            // 4 MiB
    short* Vpk = (short*)(ws + 50331648);            // 4 MiB

    cvt_x<<<8192, 256, 0, stream>>>(hs, Xbf);
    transpose_w<<<dim3(64, 64), 256, 0, stream>>>(Wq, WqT, 2048, 2048);
    transpose_w<<<dim3(16, 64), 256, 0, stream>>>(Wk, WkT, 2048, 512);
    transpose_w<<<dim3(16, 64), 256, 0, stream>>>(Wv, WvT, 2048, 512);
    proj_gemm<<<dim3(32, 24), 256, 0, stream>>>(Xbf, WqT, WkT, WvT, bq, bk, bv,
                                                Qb, Kpk, Vpk);
    attn<<<4096, 256, 0, stream>>>(Qb, Kpk, Vpk, out);
}